// Round 7
// baseline (429.949 us; speedup 1.0000x reference)
//
#include <hip/hip_runtime.h>
#include <hip/hip_bf16.h>

#define N 8192
#define FD 128
#define LOG2E 1.4426950408889634f
#define CMS 132   // cmask row stride (bytes), 128+4 to de-camp banks

typedef __attribute__((ext_vector_type(4))) float f4;
typedef __attribute__((ext_vector_type(4))) int i32x4;
typedef __attribute__((ext_vector_type(4))) unsigned int u32x4;
typedef __attribute__((ext_vector_type(8))) __bf16 bf16x8;

__device__ __forceinline__ unsigned short bfbits(float x){
  __bf16 b = (__bf16)x;
  return __builtin_bit_cast(unsigned short, b);
}

// ---- K12: Wh = h @ W (f32) + Bsw (MFMA-B-swizzled bf16) + fused s1L/s2L tail ----
__global__ __launch_bounds__(256) void k12_wh(const float* __restrict__ h,
                                              const float* __restrict__ W,
                                              const float* __restrict__ a,
                                              unsigned short* __restrict__ Bsw,
                                              float* __restrict__ s1L,
                                              float* __restrict__ s2L){
  __shared__ float Wl[64*128];
  __shared__ float hT[128*33];
  int t = threadIdx.x;
  int i0 = blockIdx.x * 32;
  {
    int r  = t >> 3;
    int k0 = (t & 7) * 16;
    const f4* src = (const f4*)&h[(size_t)(i0 + r)*FD + k0];
    #pragma unroll
    for (int q = 0; q < 4; ++q){
      f4 v = src[q];
      #pragma unroll
      for (int e = 0; e < 4; ++e) hT[(k0 + q*4 + e)*33 + r] = v[e];
    }
  }
  int f0 = (t & 31) * 4;
  int r0 = (t >> 5) * 4;
  float acc[4][4] = {};
  for (int half = 0; half < 2; ++half){
    __syncthreads();
    #pragma unroll
    for (int v = 0; v < 8; ++v){
      int idx = (v*256 + t)*4;
      *(f4*)&Wl[idx] = *(const f4*)&W[half*8192 + idx];
    }
    __syncthreads();
    for (int k2 = 0; k2 < 64; ++k2){
      f4 wv = *(const f4*)&Wl[k2*FD + f0];
      f4 hv = *(const f4*)&hT[(half*64 + k2)*33 + r0];
      #pragma unroll
      for (int ri = 0; ri < 4; ++ri)
        #pragma unroll
        for (int fi = 0; fi < 4; ++fi)
          acc[ri][fi] = __builtin_fmaf(hv[ri], wv[fi], acc[ri][fi]);
    }
  }
  int jblk = blockIdx.x;
  int n  = f0 >> 4;
  int fl = f0 & 15;
  #pragma unroll
  for (int ri = 0; ri < 4; ++ri){
    int k = r0 + ri;
    size_t base = (((size_t)jblk*8 + n)*64 + ((k>>3)<<4))*8 + (k&7);
    #pragma unroll
    for (int fi = 0; fi < 4; ++fi)
      Bsw[base + (size_t)(fl + fi)*8] = bfbits(acc[ri][fi]);
  }
  f4 a1v = *(const f4*)&a[f0];
  f4 a2v = *(const f4*)&a[FD + f0];
  float p1[4], p2[4];
  #pragma unroll
  for (int ri = 0; ri < 4; ++ri){
    p1[ri] = 0.f; p2[ri] = 0.f;
    #pragma unroll
    for (int fi = 0; fi < 4; ++fi){
      p1[ri] = __builtin_fmaf(acc[ri][fi], a1v[fi], p1[ri]);
      p2[ri] = __builtin_fmaf(acc[ri][fi], a2v[fi], p2[ri]);
    }
  }
  #pragma unroll
  for (int d = 1; d < 32; d <<= 1){
    #pragma unroll
    for (int ri = 0; ri < 4; ++ri){
      p1[ri] += __shfl_xor(p1[ri], d, 32);
      p2[ri] += __shfl_xor(p2[ri], d, 32);
    }
  }
  if ((t & 31) == 0){
    #pragma unroll
    for (int ri = 0; ri < 4; ++ri){
      s1L[i0 + r0 + ri] = p1[ri] * LOG2E;
      s2L[i0 + r0 + ri] = p2[ri] * LOG2E;
    }
  }
}

// ---------------- K3: M2L = max(s2L) ----------------
__global__ __launch_bounds__(256) void k3_max(const float* __restrict__ s2L,
                                              float* __restrict__ M2L){
  __shared__ float red[4];
  int t = threadIdx.x;
  float m = -3.0e38f;
  for (int i = t; i < N; i += 256) m = fmaxf(m, s2L[i]);
  #pragma unroll
  for (int d = 1; d < 64; d <<= 1) m = fmaxf(m, __shfl_xor(m, d, 64));
  if ((t & 63) == 0) red[t >> 6] = m;
  __syncthreads();
  if (t == 0) *M2L = fmaxf(fmaxf(red[0], red[1]), fmaxf(red[2], red[3]));
}

// ---- K4 v6: bulk adj pre-stage (full-channel 4KB-row reads) + L2 Bsw pipeline ----
// Block = 256 thr (4 waves), 128 rows x 1024-j segment(s). Per segment:
//  (1) bulk-stage adj 128x1024 -> 16.5KB LDS bitmask (cmask, consumer order)
//      rows read as full 4KB chunks -> all HBM channels hot; one burst.
//  (2) 16 macros of 64 j: GLDS-dbuf Bsw slice (L2-resident, XCD-aligned y),
//      masks+s2 from LDS, 2 js-tiles x 18 MFMA, ONE barrier per macro.
__global__ __launch_bounds__(256,3) void k4_flash(const int* __restrict__ adj,
    const unsigned short* __restrict__ Bsw,
    const float* __restrict__ s1L, const float* __restrict__ s2L,
    const float* __restrict__ M2p,
    float* __restrict__ partial, float* __restrict__ denomp, int njc){
  __shared__ __align__(16) unsigned char bswl[2][16384];
  __shared__ __align__(16) unsigned char cmask[128*CMS];
  __shared__ __align__(16) float s2l[2][64];
  int t = threadIdx.x;
  int wv = t >> 6, lane = t & 63;
  int lrow = lane & 15, lgrp = lane >> 4;
  int bid = blockIdx.x;
  int y  = bid & (njc - 1);          // njc pow2; =8 aligns j-chunks with XCDs
  int bx = bid / njc;
  int jlen = N / njc;
  int jstart = y * jlen;
  int nseg = jlen >> 10;
  float M2 = *M2p;
  int i0w = bx*128 + wv*32;
  float s1a = s1L[i0w + lrow], s1b = s1L[i0w + 16 + lrow];
  float ea = s1a + M2, eb = s1b + M2;
  float maL = fmaxf(ea, 0.2f*ea);
  float mbL = fmaxf(eb, 0.2f*eb);

  u32x4 onesbits = (u32x4){0x3F803F80u,0x3F803F80u,0x3F803F80u,0x3F803F80u};
  bf16x8 ones = __builtin_bit_cast(bf16x8, onesbits);
  const i32x4* adj4 = (const i32x4*)adj;

  #define STAGE_BSW64(jb0, b) do {                                             \
    const unsigned int* bg = (const unsigned int*)(Bsw + (size_t)((jb0) >> 5) * 4096); \
    _Pragma("unroll")                                                          \
    for (int q = 0; q < 4; ++q){                                               \
      int chunk = q*4 + wv;                                                    \
      __builtin_amdgcn_global_load_lds(                                        \
        (const __attribute__((address_space(1))) unsigned int*)(bg + (size_t)(chunk*64 + lane)*4), \
        (__attribute__((address_space(3))) unsigned int*)(&bswl[b][0] + chunk*1024), \
        16, 0, 0);                                                             \
    }                                                                          \
  } while(0)

  f4 acc[2][8]; f4 accd[2];
  #pragma unroll
  for (int x = 0; x < 2; ++x){
    accd[x] = (f4){0.f,0.f,0.f,0.f};
    #pragma unroll
    for (int n = 0; n < 8; ++n) acc[x][n] = (f4){0.f,0.f,0.f,0.f};
  }

  int crowA = wv*32 + lrow;          // this thread's mask rows (local)
  int crowB = crowA + 16;

  for (int seg = 0; seg < nseg; ++seg){
    int segj = jstart + seg*1024;
    if (seg > 0) __syncthreads();    // protect cmask from previous readers
    // ---- (1) bulk adj stage: wave covers 32 rows x full 1024-j (4KB/row) ----
    {
      size_t rb4 = (((size_t)(bx*128 + wv*32)) * 2048) + (size_t)(segj >> 2);
      for (int rb = 0; rb < 8; ++rb){
        i32x4 ld[4][4];
        #pragma unroll
        for (int rr = 0; rr < 4; ++rr){
          size_t base = rb4 + (size_t)(rb*4 + rr)*2048;
          ld[rr][0] = adj4[base + lane*2];
          ld[rr][1] = adj4[base + lane*2 + 1];
          ld[rr][2] = adj4[base + 128 + lane*2];
          ld[rr][3] = adj4[base + 128 + lane*2 + 1];
        }
        #pragma unroll
        for (int rr = 0; rr < 4; ++rr){
          int crow = wv*32 + rb*4 + rr;
          unsigned b0 = 0, b1 = 0;
          #pragma unroll
          for (int e = 0; e < 4; ++e){
            b0 |= (ld[rr][0][e] != 0 ? 1u : 0u) << e;
            b0 |= (ld[rr][1][e] != 0 ? 1u : 0u) << (4+e);
            b1 |= (ld[rr][2][e] != 0 ? 1u : 0u) << e;
            b1 |= (ld[rr][3][e] != 0 ? 1u : 0u) << (4+e);
          }
          int w0 = lane, w1 = 64 + lane;   // j-window = j/8 within segment
          cmask[crow*CMS + (w0&3)*32 + ((w0>>3)&15)*2 + ((w0>>2)&1)] = (unsigned char)b0;
          cmask[crow*CMS + (w1&3)*32 + ((w1>>3)&15)*2 + ((w1>>2)&1)] = (unsigned char)b1;
        }
      }
    }
    __syncthreads();
    // ---- (2) macro pipeline: 16 x 64-j, Bsw GLDS dbuf from L2 ----
    int buf = 0;
    STAGE_BSW64(segj, 0);
    if (t < 16) *(f4*)&s2l[0][t*4] = *(const f4*)&s2L[segj + t*4];
    __syncthreads();
    for (int m = 0; m < 16; ++m){
      int jb0 = segj + m*64;
      if (m < 15){
        STAGE_BSW64(jb0 + 64, buf ^ 1);
        if (t < 16) *(f4*)&s2l[buf ^ 1][t*4] = *(const f4*)&s2L[jb0 + 64 + t*4];
      }
      int moff = lgrp*32 + m*2;
      unsigned ua = *(const unsigned short*)&cmask[crowA*CMS + moff];
      unsigned ub = *(const unsigned short*)&cmask[crowB*CMS + moff];
      #pragma unroll
      for (int js = 0; js < 2; ++js){
        int jo = js*32 + lgrp*8;
        f4 ya = *(const f4*)&s2l[buf][jo];
        f4 yb = *(const f4*)&s2l[buf][jo+4];
        unsigned mba = (ua >> (js*8)) & 0xFFu;
        unsigned mbb = (ub >> (js*8)) & 0xFFu;
        bf16x8 fa, fb;
        #pragma unroll
        for (int e = 0; e < 8; ++e){
          float sjv = (e < 4) ? ya[e] : yb[e-4];
          float xa = s1a + sjv,            xb = s1b + sjv;
          float la = fmaxf(xa, 0.2f*xa),   lb = fmaxf(xb, 0.2f*xb);
          float pa = ((mba>>e)&1u) ? __builtin_amdgcn_exp2f(la - maL) : 0.f;
          float pb = ((mbb>>e)&1u) ? __builtin_amdgcn_exp2f(lb - mbL) : 0.f;
          fa[e] = (__bf16)pa; fb[e] = (__bf16)pb;
        }
        accd[0] = __builtin_amdgcn_mfma_f32_16x16x32_bf16(fa, ones, accd[0], 0, 0, 0);
        accd[1] = __builtin_amdgcn_mfma_f32_16x16x32_bf16(fb, ones, accd[1], 0, 0, 0);
        {
          u32x4 b0[4];
          #pragma unroll
          for (int n = 0; n < 4; ++n)
            b0[n] = *(const u32x4*)&bswl[buf][((js*8 + n)*64 + lane)*16];
          #pragma unroll
          for (int n = 0; n < 4; ++n){
            bf16x8 bb = __builtin_bit_cast(bf16x8, b0[n]);
            acc[0][n] = __builtin_amdgcn_mfma_f32_16x16x32_bf16(fa, bb, acc[0][n], 0, 0, 0);
            acc[1][n] = __builtin_amdgcn_mfma_f32_16x16x32_bf16(fb, bb, acc[1][n], 0, 0, 0);
          }
        }
        {
          u32x4 b1[4];
          #pragma unroll
          for (int n = 0; n < 4; ++n)
            b1[n] = *(const u32x4*)&bswl[buf][((js*8 + 4 + n)*64 + lane)*16];
          #pragma unroll
          for (int n = 0; n < 4; ++n){
            bf16x8 bb = __builtin_bit_cast(bf16x8, b1[n]);
            acc[0][4+n] = __builtin_amdgcn_mfma_f32_16x16x32_bf16(fa, bb, acc[0][4+n], 0, 0, 0);
            acc[1][4+n] = __builtin_amdgcn_mfma_f32_16x16x32_bf16(fb, bb, acc[1][4+n], 0, 0, 0);
          }
        }
      }
      __syncthreads();
      buf ^= 1;
    }
  }

  if (lrow == 0){
    #pragma unroll
    for (int x = 0; x < 2; ++x)
      #pragma unroll
      for (int r = 0; r < 4; ++r)
        denomp[(size_t)y*N + i0w + x*16 + lgrp*4 + r] = accd[x][r];
  }
  float* pb = partial + (size_t)y * N * FD;
  #pragma unroll
  for (int x = 0; x < 2; ++x)
    #pragma unroll
    for (int n = 0; n < 8; ++n)
      #pragma unroll
      for (int r = 0; r < 4; ++r)
        pb[(size_t)(i0w + x*16 + lgrp*4 + r)*FD + n*16 + lrow] = acc[x][n][r];
}

// ---------------- K5: combine partials, divide ----------------
__global__ __launch_bounds__(256) void k5_fin(const float* __restrict__ partial,
    const float* __restrict__ denomp, float* __restrict__ out, int njc){
  int g = blockIdx.x*256 + threadIdx.x;
  int i = g >> 7;
  float num = 0.f, den = 0.f;
  for (int c = 0; c < njc; ++c) num += partial[(size_t)c*N*FD + g];
  for (int c = 0; c < njc; ++c) den += denomp[(size_t)c*N + i];
  out[g] = num / den;
}

extern "C" void kernel_launch(void* const* d_in, const int* in_sizes, int n_in,
                              void* d_out, int out_size, void* d_ws, size_t ws_size,
                              hipStream_t stream){
  const float* h   = (const float*)d_in[0];
  const int*   adj = (const int*)d_in[1];
  const float* W   = (const float*)d_in[2];
  const float* a   = (const float*)d_in[3];
  float* out = (float*)d_out;
  char* ws = (char*)d_ws;

  unsigned short* Bsw = (unsigned short*)ws;             // 2 MB
  float* s1L = (float*)(ws + (size_t)(6u<<20));          // 32 KB
  float* s2L = (float*)(ws + (size_t)(6u<<20) + 32768);  // 32 KB
  float* M2L = (float*)(ws + (size_t)(6u<<20) + 65536);  // 4 B
  float* denomp  = (float*)(ws + (size_t)(7u<<20));      // njc*32 KB
  float* partial = (float*)(ws + (size_t)(8u<<20));      // njc*4 MB

  size_t chunk = (size_t)N * FD * sizeof(float);         // 4 MB
  int njc = 1;
  if (ws_size > ((size_t)(8u<<20))){
    size_t m = (ws_size - (size_t)(8u<<20)) / chunk;
    njc = (m >= 8) ? 8 : (m >= 4) ? 4 : (m >= 2) ? 2 : 1;
  }

  hipLaunchKernelGGL(k12_wh, dim3(256), dim3(256), 0, stream, h, W, a, Bsw, s1L, s2L);
  hipLaunchKernelGGL(k3_max, dim3(1),   dim3(256), 0, stream, s2L, M2L);
  hipLaunchKernelGGL(k4_flash, dim3(64*njc), dim3(256), 0, stream,
                     adj, Bsw, s1L, s2L, M2L, partial, denomp, njc);
  hipLaunchKernelGGL(k5_fin, dim3(N*FD/256), dim3(256), 0, stream, partial, denomp, out, njc);
}

// Round 8
// 392.337 us; speedup vs baseline: 1.0959x; 1.0959x over previous
//
#include <hip/hip_runtime.h>
#include <hip/hip_bf16.h>

#define N 8192
#define FD 128
#define LOG2E 1.4426950408889634f

typedef __attribute__((ext_vector_type(4))) float f4;
typedef __attribute__((ext_vector_type(4))) int i32x4;
typedef __attribute__((ext_vector_type(4))) unsigned int u32x4;
typedef __attribute__((ext_vector_type(8))) __bf16 bf16x8;

__device__ __forceinline__ unsigned short bfbits(float x){
  __bf16 b = (__bf16)x;
  return __builtin_bit_cast(unsigned short, b);
}

// ---- K12: Wh = h @ W (f32) + Bsw (MFMA-B-swizzled bf16) + fused s1L/s2L tail ----
// Bsw flat layout: elem(jblk, n, lane, e) at ((jblk*8+n)*64 + lane)*8 + e
//   holds bf16( Wh[jblk*32 + (lane>>4)*8 + e][n*16 + (lane&15)] )
__global__ __launch_bounds__(256) void k12_wh(const float* __restrict__ h,
                                              const float* __restrict__ W,
                                              const float* __restrict__ a,
                                              unsigned short* __restrict__ Bsw,
                                              float* __restrict__ s1L,
                                              float* __restrict__ s2L){
  __shared__ float Wl[64*128];
  __shared__ float hT[128*33];
  int t = threadIdx.x;
  int i0 = blockIdx.x * 32;
  {
    int r  = t >> 3;
    int k0 = (t & 7) * 16;
    const f4* src = (const f4*)&h[(size_t)(i0 + r)*FD + k0];
    #pragma unroll
    for (int q = 0; q < 4; ++q){
      f4 v = src[q];
      #pragma unroll
      for (int e = 0; e < 4; ++e) hT[(k0 + q*4 + e)*33 + r] = v[e];
    }
  }
  int f0 = (t & 31) * 4;
  int r0 = (t >> 5) * 4;
  float acc[4][4] = {};
  for (int half = 0; half < 2; ++half){
    __syncthreads();
    #pragma unroll
    for (int v = 0; v < 8; ++v){
      int idx = (v*256 + t)*4;
      *(f4*)&Wl[idx] = *(const f4*)&W[half*8192 + idx];
    }
    __syncthreads();
    for (int k2 = 0; k2 < 64; ++k2){
      f4 wv = *(const f4*)&Wl[k2*FD + f0];
      f4 hv = *(const f4*)&hT[(half*64 + k2)*33 + r0];
      #pragma unroll
      for (int ri = 0; ri < 4; ++ri)
        #pragma unroll
        for (int fi = 0; fi < 4; ++fi)
          acc[ri][fi] = __builtin_fmaf(hv[ri], wv[fi], acc[ri][fi]);
    }
  }
  int jblk = blockIdx.x;
  int n  = f0 >> 4;
  int fl = f0 & 15;
  #pragma unroll
  for (int ri = 0; ri < 4; ++ri){
    int k = r0 + ri;
    size_t base = (((size_t)jblk*8 + n)*64 + ((k>>3)<<4))*8 + (k&7);
    #pragma unroll
    for (int fi = 0; fi < 4; ++fi)
      Bsw[base + (size_t)(fl + fi)*8] = bfbits(acc[ri][fi]);
  }
  f4 a1v = *(const f4*)&a[f0];
  f4 a2v = *(const f4*)&a[FD + f0];
  float p1[4], p2[4];
  #pragma unroll
  for (int ri = 0; ri < 4; ++ri){
    p1[ri] = 0.f; p2[ri] = 0.f;
    #pragma unroll
    for (int fi = 0; fi < 4; ++fi){
      p1[ri] = __builtin_fmaf(acc[ri][fi], a1v[fi], p1[ri]);
      p2[ri] = __builtin_fmaf(acc[ri][fi], a2v[fi], p2[ri]);
    }
  }
  #pragma unroll
  for (int d = 1; d < 32; d <<= 1){
    #pragma unroll
    for (int ri = 0; ri < 4; ++ri){
      p1[ri] += __shfl_xor(p1[ri], d, 32);
      p2[ri] += __shfl_xor(p2[ri], d, 32);
    }
  }
  if ((t & 31) == 0){
    #pragma unroll
    for (int ri = 0; ri < 4; ++ri){
      s1L[i0 + r0 + ri] = p1[ri] * LOG2E;
      s2L[i0 + r0 + ri] = p2[ri] * LOG2E;
    }
  }
}

// ---------------- K3: M2L = max(s2L) ----------------
__global__ __launch_bounds__(256) void k3_max(const float* __restrict__ s2L,
                                              float* __restrict__ M2L){
  __shared__ float red[4];
  int t = threadIdx.x;
  float m = -3.0e38f;
  for (int i = t; i < N; i += 256) m = fmaxf(m, s2L[i]);
  #pragma unroll
  for (int d = 1; d < 64; d <<= 1) m = fmaxf(m, __shfl_xor(m, d, 64));
  if ((t & 63) == 0) red[t >> 6] = m;
  __syncthreads();
  if (t == 0) *M2L = fmaxf(fmaxf(red[0], red[1]), fmaxf(red[2], red[3]));
}

// -- K4 v7: v5's 2-phase dbuf pipeline + PER-BLOCK MACRO ROTATION (channel fix) --
// Block = 256 thr (4 waves), 128 rows x one j-chunk. Macro visit order is
// rotated by bx: pm = (m + bx) & (nmac-1). At any instant the 64 bx values x
// 8 XCD y-chunks cover the FULL 32KB row-period -> all HBM channels hot.
// Stage macro pm(m+1) (async Bsw GLDS + coalesced adj->regs) BEFORE computing
// pm(m); pack masks after compute; ONE barrier per macro.
__global__ __launch_bounds__(256,2) void k4_flash(const int* __restrict__ adj,
    const unsigned short* __restrict__ Bsw,
    const float* __restrict__ s1L, const float* __restrict__ s2L,
    const float* __restrict__ M2p,
    float* __restrict__ partial, float* __restrict__ denomp, int njc){
  __shared__ __align__(16) unsigned char bswl[2][32768];
  __shared__ __align__(16) unsigned char mknib[2][128*32];
  __shared__ __align__(16) float s2l[2][128];
  int t = threadIdx.x;
  int wv = t >> 6, lane = t & 63;
  int lrow = lane & 15, lgrp = lane >> 4;
  int bid = blockIdx.x;
  int y  = bid & (njc - 1);        // njc pow2; =8 aligns j-chunks with XCDs
  int bx = bid / njc;
  int jlen = N / njc;
  int jstart = y * jlen;
  int nmac = jlen >> 7;            // pow2
  int rotm = nmac - 1;
  float M2 = *M2p;
  int i0w = bx*128 + wv*32;
  float s1a = s1L[i0w + lrow], s1b = s1L[i0w + 16 + lrow];
  float ea = s1a + M2, eb = s1b + M2;
  float maL = fmaxf(ea, 0.2f*ea);
  float mbL = fmaxf(eb, 0.2f*eb);

  f4 acc[2][8]; f4 accd[2];
  #pragma unroll
  for (int x = 0; x < 2; ++x){
    accd[x] = (f4){0.f,0.f,0.f,0.f};
    #pragma unroll
    for (int n = 0; n < 8; ++n) acc[x][n] = (f4){0.f,0.f,0.f,0.f};
  }
  u32x4 onesbits = (u32x4){0x3F803F80u,0x3F803F80u,0x3F803F80u,0x3F803F80u};
  bf16x8 ones = __builtin_bit_cast(bf16x8, onesbits);

  const i32x4* adj4 = (const i32x4*)adj;
  int sr2 = lane >> 5;                 // staging row parity
  int sj  = lane & 31;                 // 4-int group within 128-j macro
  size_t abase = ((size_t)(bx*128 + wv*32 + sr2) * N) >> 2;   // i32x4 units

  i32x4 st[16];

  #define STAGE_BSW(jb0, b) do {                                               \
    const unsigned int* bg = (const unsigned int*)(Bsw + (size_t)((jb0) >> 5) * 4096); \
    _Pragma("unroll")                                                          \
    for (int q = 0; q < 8; ++q){                                               \
      int chunk = q*4 + wv;                                                    \
      __builtin_amdgcn_global_load_lds(                                        \
        (const __attribute__((address_space(1))) unsigned int*)(bg + (size_t)(chunk*64 + lane)*4), \
        (__attribute__((address_space(3))) unsigned int*)(&bswl[b][0] + chunk*1024), \
        16, 0, 0);                                                             \
    }                                                                          \
  } while(0)

  #define STAGE_ADJ(jb0) do {                                                  \
    size_t ab = abase + (size_t)((jb0) >> 2) + sj;                             \
    _Pragma("unroll")                                                          \
    for (int e = 0; e < 16; ++e) st[e] = adj4[ab + (size_t)e * 4096];          \
  } while(0)

  #define PACK_MASKS(b) do {                                                   \
    _Pragma("unroll")                                                          \
    for (int e = 0; e < 16; ++e){                                              \
      unsigned nib = (st[e][0] != 0 ? 1u : 0u) | (st[e][1] != 0 ? 2u : 0u)     \
                   | (st[e][2] != 0 ? 4u : 0u) | (st[e][3] != 0 ? 8u : 0u);    \
      int rloc = wv*32 + e*2 + sr2;                                            \
      mknib[b][rloc*32 + sj] = (unsigned char)nib;                             \
    }                                                                          \
  } while(0)

  // ---- prologue: stage rotated macro 0 into buf 0 ----
  int buf = 0;
  int jb_first = jstart + ((bx) & rotm) * 128;
  STAGE_BSW(jb_first, 0);
  STAGE_ADJ(jb_first);
  PACK_MASKS(0);
  if (t < 32) *(f4*)&s2l[0][t*4] = *(const f4*)&s2L[jb_first + t*4];
  __syncthreads();

  for (int m = 0; m < nmac; ++m){
    int jb0 = jstart + ((m + bx) & rotm) * 128;       // rotated macro (current)
    int jb1 = jstart + ((m + 1 + bx) & rotm) * 128;   // rotated macro (next)
    // ---- issue next macro's stage BEFORE compute (pipeline) ----
    if (m + 1 < nmac){
      STAGE_BSW(jb1, buf ^ 1);
      STAGE_ADJ(jb1);
    }
    // ---- compute current macro from LDS buf ----
    #pragma unroll
    for (int js = 0; js < 4; ++js){
      int jo = js*32 + lgrp*8;
      f4 ya = *(const f4*)&s2l[buf][jo];
      f4 yb = *(const f4*)&s2l[buf][jo+4];
      int gb = (js*4 + lgrp)*2;
      unsigned short ua = *(const unsigned short*)&mknib[buf][(wv*32 + lrow)*32 + gb];
      unsigned short ub = *(const unsigned short*)&mknib[buf][(wv*32 + 16 + lrow)*32 + gb];
      unsigned mba = (ua & 0xFu) | ((ua >> 4) & 0xF0u);
      unsigned mbb = (ub & 0xFu) | ((ub >> 4) & 0xF0u);
      bf16x8 fa, fb;
      #pragma unroll
      for (int e = 0; e < 8; ++e){
        float sjv = (e < 4) ? ya[e] : yb[e-4];
        float xa = s1a + sjv,            xb = s1b + sjv;
        float la = fmaxf(xa, 0.2f*xa),   lb = fmaxf(xb, 0.2f*xb);
        float pa = ((mba>>e)&1u) ? __builtin_amdgcn_exp2f(la - maL) : 0.f;
        float pb = ((mbb>>e)&1u) ? __builtin_amdgcn_exp2f(lb - mbL) : 0.f;
        fa[e] = (__bf16)pa; fb[e] = (__bf16)pb;
      }
      accd[0] = __builtin_amdgcn_mfma_f32_16x16x32_bf16(fa, ones, accd[0], 0, 0, 0);
      accd[1] = __builtin_amdgcn_mfma_f32_16x16x32_bf16(fb, ones, accd[1], 0, 0, 0);
      {
        u32x4 b0[4];
        #pragma unroll
        for (int n = 0; n < 4; ++n)
          b0[n] = *(const u32x4*)&bswl[buf][((js*8 + n)*64 + lane)*16];
        #pragma unroll
        for (int n = 0; n < 4; ++n){
          bf16x8 bb = __builtin_bit_cast(bf16x8, b0[n]);
          acc[0][n] = __builtin_amdgcn_mfma_f32_16x16x32_bf16(fa, bb, acc[0][n], 0, 0, 0);
          acc[1][n] = __builtin_amdgcn_mfma_f32_16x16x32_bf16(fb, bb, acc[1][n], 0, 0, 0);
        }
      }
      {
        u32x4 b1[4];
        #pragma unroll
        for (int n = 0; n < 4; ++n)
          b1[n] = *(const u32x4*)&bswl[buf][((js*8 + 4 + n)*64 + lane)*16];
        #pragma unroll
        for (int n = 0; n < 4; ++n){
          bf16x8 bb = __builtin_bit_cast(bf16x8, b1[n]);
          acc[0][4+n] = __builtin_amdgcn_mfma_f32_16x16x32_bf16(fa, bb, acc[0][4+n], 0, 0, 0);
          acc[1][4+n] = __builtin_amdgcn_mfma_f32_16x16x32_bf16(fb, bb, acc[1][4+n], 0, 0, 0);
        }
      }
    }
    // ---- land next macro's masks/s2 into the other buffer, then one barrier ----
    if (m + 1 < nmac){
      PACK_MASKS(buf ^ 1);
      if (t < 32) *(f4*)&s2l[buf ^ 1][t*4] = *(const f4*)&s2L[jb1 + t*4];
    }
    __syncthreads();
    buf ^= 1;
  }

  if (lrow == 0){
    #pragma unroll
    for (int x = 0; x < 2; ++x)
      #pragma unroll
      for (int r = 0; r < 4; ++r)
        denomp[(size_t)y*N + i0w + x*16 + lgrp*4 + r] = accd[x][r];
  }
  float* pb = partial + (size_t)y * N * FD;
  #pragma unroll
  for (int x = 0; x < 2; ++x)
    #pragma unroll
    for (int n = 0; n < 8; ++n)
      #pragma unroll
      for (int r = 0; r < 4; ++r)
        pb[(size_t)(i0w + x*16 + lgrp*4 + r)*FD + n*16 + lrow] = acc[x][n][r];
}

// ---------------- K5: combine partials, divide ----------------
__global__ __launch_bounds__(256) void k5_fin(const float* __restrict__ partial,
    const float* __restrict__ denomp, float* __restrict__ out, int njc){
  int g = blockIdx.x*256 + threadIdx.x;
  int i = g >> 7;
  float num = 0.f, den = 0.f;
  for (int c = 0; c < njc; ++c) num += partial[(size_t)c*N*FD + g];
  for (int c = 0; c < njc; ++c) den += denomp[(size_t)c*N + i];
  out[g] = num / den;
}

extern "C" void kernel_launch(void* const* d_in, const int* in_sizes, int n_in,
                              void* d_out, int out_size, void* d_ws, size_t ws_size,
                              hipStream_t stream){
  const float* h   = (const float*)d_in[0];
  const int*   adj = (const int*)d_in[1];
  const float* W   = (const float*)d_in[2];
  const float* a   = (const float*)d_in[3];
  float* out = (float*)d_out;
  char* ws = (char*)d_ws;

  unsigned short* Bsw = (unsigned short*)ws;             // 2 MB
  float* s1L = (float*)(ws + (size_t)(6u<<20));          // 32 KB
  float* s2L = (float*)(ws + (size_t)(6u<<20) + 32768);  // 32 KB
  float* M2L = (float*)(ws + (size_t)(6u<<20) + 65536);  // 4 B
  float* denomp  = (float*)(ws + (size_t)(7u<<20));      // njc*32 KB
  float* partial = (float*)(ws + (size_t)(8u<<20));      // njc*4 MB

  size_t chunk = (size_t)N * FD * sizeof(float);         // 4 MB
  int njc = 1;
  if (ws_size > ((size_t)(8u<<20))){
    size_t m = (ws_size - (size_t)(8u<<20)) / chunk;
    njc = (m >= 8) ? 8 : (m >= 4) ? 4 : (m >= 2) ? 2 : 1;
  }

  hipLaunchKernelGGL(k12_wh, dim3(256), dim3(256), 0, stream, h, W, a, Bsw, s1L, s2L);
  hipLaunchKernelGGL(k3_max, dim3(1),   dim3(256), 0, stream, s2L, M2L);
  hipLaunchKernelGGL(k4_flash, dim3(64*njc), dim3(256), 0, stream,
                     adj, Bsw, s1L, s2L, M2L, partial, denomp, njc);
  hipLaunchKernelGGL(k5_fin, dim3(N*FD/256), dim3(256), 0, stream, partial, denomp, out, njc);
}